// Round 23
// baseline (134.991 us; speedup 1.0000x reference)
//
#include <hip/hip_runtime.h>
#include <hip/hip_bf16.h>
#include <math.h>

#define E_EDGES 1000000
#define N_NODES 50000
#define N_C     64
#define N_REL   8
#define CHB     4096        // edges per block
#define CAP     640         // per-rel LDS capacity (mean 512, sigma 21 -> 6 sigma)
#define NBLK    245         // ceil(1e6 / 4096)
#define BT      1024        // 16 waves per block -> ~30 waves/CU ideal

typedef __attribute__((ext_vector_type(4))) float floatx4;
typedef __attribute__((ext_vector_type(2))) float floatx2;

// pack 4 fp32 -> 4 fp8 e4m3 (RNE); byte j = element j
static __device__ __forceinline__ unsigned pk4_fp8(float a, float b, float c, float d) {
    unsigned w = 0;
    w = __builtin_amdgcn_cvt_pk_fp8_f32(a, b, w, false);
    w = __builtin_amdgcn_cvt_pk_fp8_f32(c, d, w, true);
    return w;
}

static __device__ __forceinline__ long long pack64(unsigned lo, unsigned hi) {
    uint2 u; u.x = lo; u.y = hi;
    return __builtin_bit_cast(long long, u);
}

// kappa slot permutation (verified R11/R12): Wp8 byte (q*16 + c*8 + j) of row
// holds fp8(W[row][(2c+(j>>2))*16 + 4q + (j&3)]); AS8 row byte q*16+u holds
// elem (u>>2)*16 + 4q + (u&3). One b128 per lane serves both the MFMA B-op
// and the src dot.
__global__ __launch_bounds__(256) void prep_kernel(
    const float* __restrict__ assign,
    const float* __restrict__ icl,
    const float* __restrict__ la,
    unsigned char* __restrict__ Wp8,
    unsigned char* __restrict__ AS8,
    float* __restrict__ out)
{
    int tid = blockIdx.x * blockDim.x + threadIdx.x;
    int nth = gridDim.x * blockDim.x;
    if (tid == 0) out[0] = 0.0f;

    // Wp8: one thread per output dword (512 rows x 16 dwords)
    for (int idx = tid; idx < N_REL * N_C * 16; idx += nth) {
        int row = idx >> 4, dq = idx & 15;
        int q = dq >> 2, c = (dq >> 1) & 1, jh = dq & 1;
        int k0 = (2 * c + jh) * 16 + 4 * q;   // bytes b=0..3 -> k = k0 + b
        float wv[4];
        #pragma unroll
        for (int b = 0; b < 4; ++b) {
            int srci = (row << 6) + k0 + b;
            float w = 1.0f / (1.0f + __expf(-icl[srci]));
            float g = 1.0f / (1.0f + __expf(-la[srci])) * 1.2f - 0.1f;
            g = fminf(fmaxf(g, 0.0f), 1.0f);
            wv[b] = w * g;
        }
        ((unsigned*)Wp8)[idx] = pk4_fp8(wv[0], wv[1], wv[2], wv[3]);
    }

    // AS8: one thread per node row; dword[q*4 + mt] = elems [16mt+4q, +4)
    for (int n = tid; n < N_NODES; n += nth) {
        const float4* a4 = (const float4*)(assign + (size_t)n * N_C);
        unsigned w[16];
        #pragma unroll
        for (int i = 0; i < 16; ++i) {
            float4 v = a4[i];
            w[i] = pk4_fp8(v.x, v.y, v.z, v.w);   // w[i] = elems 4i..4i+3
        }
        uint4* as = (uint4*)(AS8 + (size_t)n * N_C);
        #pragma unroll
        for (int q = 0; q < 4; ++q) {
            uint4 o;
            o.x = w[0 * 4 + q];
            o.y = w[1 * 4 + q];
            o.z = w[2 * 4 + q];
            o.w = w[3 * 4 + q];
            as[q] = o;
        }
    }
}

// Fused edge pass (R22 body, 1024-thread blocks): bin CHB edges by relation
// in LDS, then per relation MFMA-batch 16 edges/wave (native fp8 MFMA,
// stationary W, S/D register prefetch). 490 blocks x 16 waves ~ 30 waves/CU.
__global__ __launch_bounds__(BT, 8) void edge_kernel(
    const unsigned char* __restrict__ AS8,
    const unsigned char* __restrict__ Wp8,
    const float* __restrict__ absent_bias,
    const int* __restrict__ ei, const int* __restrict__ et,
    const int* __restrict__ nei, const int* __restrict__ net,
    float* __restrict__ out)
{
    __shared__ unsigned list[N_REL * CAP];   // 20480 B
    __shared__ unsigned cnt[N_REL];
    __shared__ float red[16];
    if (threadIdx.x < N_REL) cnt[threadIdx.x] = 0u;
    __syncthreads();

    int blk = blockIdx.x;
    bool isneg = blk >= NBLK;
    int lb = isneg ? blk - NBLK : blk;
    const int* Es = isneg ? nei : ei;
    const int* Et = isneg ? net : et;
    float sign = isneg ? 1.0f : -1.0f;
    int base = lb * CHB;
    int elim = min(base + CHB, E_EDGES);

    for (int e = base + threadIdx.x; e < elim; e += BT) {
        int s = Es[e];
        int d = Es[E_EDGES + e];
        int r = Et[e];
        unsigned rank = atomicAdd(&cnt[r], 1u);
        if (rank < CAP) list[r * CAP + rank] = (unsigned)s | ((unsigned)d << 16);
    }
    __syncthreads();

    int lane = threadIdx.x & 63;
    int wid  = threadIdx.x >> 6;    // 0..15
    int n16  = lane & 15;
    int quad = lane >> 4;
    float loss = 0.0f;

    for (int r = 0; r < N_REL; ++r) {
        int n_r = min((int)cnt[r], CAP);
        if (n_r == 0) continue;
        float bias = absent_bias[r];
        // stationary fp8 A-operand: one b128 per mt row-tile (kept in VGPRs)
        uint4 wfm[4];
        #pragma unroll
        for (int mt = 0; mt < 4; ++mt)
            wfm[mt] = *(const uint4*)(Wp8 + ((r * 64 + mt * 16 + n16) << 6) + quad * 16);

        // pipelined group loop (stride 16 waves): prefetch next group's S/D
        int g = wid;
        bool valid = false;
        uint4 S = {0, 0, 0, 0}, D = {0, 0, 0, 0};
        if (g * 16 < n_r) {
            int idx = g * 16 + n16;
            valid = idx < n_r;
            unsigned rec = list[r * CAP + (valid ? idx : 0)];
            S = *(const uint4*)(AS8 + ((size_t)(rec & 0xFFFF) << 6) + quad * 16);
            D = *(const uint4*)(AS8 + ((size_t)(rec >> 16) << 6) + quad * 16);
        }
        while (g * 16 < n_r) {
            int g2 = g + 16;
            bool valid2 = false;
            uint4 S2 = {0, 0, 0, 0}, D2 = {0, 0, 0, 0};
            if (g2 * 16 < n_r) {
                int idx2 = g2 * 16 + n16;
                valid2 = idx2 < n_r;
                unsigned rec2 = list[r * CAP + (valid2 ? idx2 : 0)];
                S2 = *(const uint4*)(AS8 + ((size_t)(rec2 & 0xFFFF) << 6) + quad * 16);
                D2 = *(const uint4*)(AS8 + ((size_t)(rec2 >> 16) << 6) + quad * 16);
            }

            long long bD0 = pack64(D.x, D.y);   // c=0 slots (first K=32)
            long long bD1 = pack64(D.z, D.w);   // c=1 slots
            floatx4 ac[4];
            #pragma unroll
            for (int mt = 0; mt < 4; ++mt) {
                floatx4 z = {0.0f, 0.0f, 0.0f, 0.0f};
                z = __builtin_amdgcn_mfma_f32_16x16x32_fp8_fp8(
                        pack64(wfm[mt].x, wfm[mt].y), bD0, z, 0, 0, 0);
                ac[mt] = __builtin_amdgcn_mfma_f32_16x16x32_fp8_fp8(
                        pack64(wfm[mt].z, wfm[mt].w), bD1, z, 0, 0, 0);
            }
            // lane holds P[m = mt*16 + quad*4 + reg][n16]; S dword mt = those m's
            unsigned sw[4] = {S.x, S.y, S.z, S.w};
            float d0 = 0.0f, d1 = 0.0f;
            #pragma unroll
            for (int mt = 0; mt < 4; mt += 2) {
                floatx2 lo0 = __builtin_amdgcn_cvt_pk_f32_fp8((int)sw[mt], false);
                floatx2 hi0 = __builtin_amdgcn_cvt_pk_f32_fp8((int)sw[mt], true);
                floatx2 lo1 = __builtin_amdgcn_cvt_pk_f32_fp8((int)sw[mt + 1], false);
                floatx2 hi1 = __builtin_amdgcn_cvt_pk_f32_fp8((int)sw[mt + 1], true);
                d0 = fmaf(lo0.x, ac[mt][0], d0);
                d1 = fmaf(lo1.x, ac[mt + 1][0], d1);
                d0 = fmaf(lo0.y, ac[mt][1], d0);
                d1 = fmaf(lo1.y, ac[mt + 1][1], d1);
                d0 = fmaf(hi0.x, ac[mt][2], d0);
                d1 = fmaf(hi1.x, ac[mt + 1][2], d1);
                d0 = fmaf(hi0.y, ac[mt][3], d0);
                d1 = fmaf(hi1.y, ac[mt + 1][3], d1);
            }
            float dot = d0 + d1;
            dot += __shfl_xor(dot, 16);
            dot += __shfl_xor(dot, 32);
            if (quad == 0 && valid) {
                float x = sign * (dot + bias);
                loss += fmaxf(x, 0.0f) + __logf(1.0f + __expf(-fabsf(x)));
            }

            g = g2; valid = valid2; S = S2; D = D2;
        }
    }

    loss += __shfl_xor(loss, 1);
    loss += __shfl_xor(loss, 2);
    loss += __shfl_xor(loss, 4);
    loss += __shfl_xor(loss, 8);
    loss += __shfl_xor(loss, 16);
    loss += __shfl_xor(loss, 32);
    if (lane == 0) red[wid] = loss;
    __syncthreads();
    if (threadIdx.x == 0) {
        float t = 0.0f;
        #pragma unroll
        for (int i = 0; i < 16; ++i) t += red[i];
        atomicAdd(out, t * (1.0f / (float)E_EDGES));
    }
}

extern "C" void kernel_launch(void* const* d_in, const int* in_sizes, int n_in,
                              void* d_out, int out_size, void* d_ws, size_t ws_size,
                              hipStream_t stream) {
    const float* assign = (const float*)d_in[0];
    const float* icl    = (const float*)d_in[1];
    const float* la     = (const float*)d_in[2];
    const float* ab     = (const float*)d_in[3];
    const int*   ei     = (const int*)d_in[4];
    const int*   et     = (const int*)d_in[5];
    const int*   nei    = (const int*)d_in[6];
    const int*   net    = (const int*)d_in[7];
    float* out = (float*)d_out;

    // workspace: Wp8 32KB (pad 64KB) | AS8 3.2MB
    char* basep = (char*)d_ws;
    unsigned char* Wp8 = (unsigned char*)basep;
    unsigned char* AS8 = (unsigned char*)(basep + 65536);

    prep_kernel<<<256, 256, 0, stream>>>(assign, icl, la, Wp8, AS8, out);
    edge_kernel<<<2 * NBLK, BT, 0, stream>>>(AS8, Wp8, ab, ei, et, nei, net, out);
}

// Round 24
// 124.567 us; speedup vs baseline: 1.0837x; 1.0837x over previous
//
#include <hip/hip_runtime.h>
#include <hip/hip_bf16.h>
#include <math.h>

#define E_EDGES 1000000
#define N_NODES 50000
#define N_C     64
#define N_REL   8
#define CHB     4096        // edges per block (amortize per-block fixed costs)
#define CAP     640         // per-rel LDS capacity (mean 512, sigma 21 -> 6 sigma)
#define NBLK    245         // ceil(1e6 / 4096)
#define BT      512         // 8 waves per block

typedef __attribute__((ext_vector_type(4))) float floatx4;
typedef __attribute__((ext_vector_type(2))) float floatx2;

// pack 4 fp32 -> 4 fp8 e4m3 (RNE); byte j = element j
static __device__ __forceinline__ unsigned pk4_fp8(float a, float b, float c, float d) {
    unsigned w = 0;
    w = __builtin_amdgcn_cvt_pk_fp8_f32(a, b, w, false);
    w = __builtin_amdgcn_cvt_pk_fp8_f32(c, d, w, true);
    return w;
}

static __device__ __forceinline__ long long pack64(unsigned lo, unsigned hi) {
    uint2 u; u.x = lo; u.y = hi;
    return __builtin_bit_cast(long long, u);
}

// kappa slot permutation (verified R11/R12): Wp8 byte (q*16 + c*8 + j) of row
// holds fp8(W[row][(2c+(j>>2))*16 + 4q + (j&3)]); AS8 row byte q*16+u holds
// elem (u>>2)*16 + 4q + (u&3). One b128 per lane serves both the MFMA B-op
// and the src dot.
__global__ __launch_bounds__(256) void prep_kernel(
    const float* __restrict__ assign,
    const float* __restrict__ icl,
    const float* __restrict__ la,
    unsigned char* __restrict__ Wp8,
    unsigned char* __restrict__ AS8,
    float* __restrict__ out)
{
    int tid = blockIdx.x * blockDim.x + threadIdx.x;
    int nth = gridDim.x * blockDim.x;
    if (tid == 0) out[0] = 0.0f;

    // Wp8: one thread per output dword (512 rows x 16 dwords)
    for (int idx = tid; idx < N_REL * N_C * 16; idx += nth) {
        int row = idx >> 4, dq = idx & 15;
        int q = dq >> 2, c = (dq >> 1) & 1, jh = dq & 1;
        int k0 = (2 * c + jh) * 16 + 4 * q;   // bytes b=0..3 -> k = k0 + b
        float wv[4];
        #pragma unroll
        for (int b = 0; b < 4; ++b) {
            int srci = (row << 6) + k0 + b;
            float w = 1.0f / (1.0f + __expf(-icl[srci]));
            float g = 1.0f / (1.0f + __expf(-la[srci])) * 1.2f - 0.1f;
            g = fminf(fmaxf(g, 0.0f), 1.0f);
            wv[b] = w * g;
        }
        ((unsigned*)Wp8)[idx] = pk4_fp8(wv[0], wv[1], wv[2], wv[3]);
    }

    // AS8: one thread per node row; dword[q*4 + mt] = elems [16mt+4q, +4)
    for (int n = tid; n < N_NODES; n += nth) {
        const float4* a4 = (const float4*)(assign + (size_t)n * N_C);
        unsigned w[16];
        #pragma unroll
        for (int i = 0; i < 16; ++i) {
            float4 v = a4[i];
            w[i] = pk4_fp8(v.x, v.y, v.z, v.w);   // w[i] = elems 4i..4i+3
        }
        uint4* as = (uint4*)(AS8 + (size_t)n * N_C);
        #pragma unroll
        for (int q = 0; q < 4; ++q) {
            uint4 o;
            o.x = w[0 * 4 + q];
            o.y = w[1 * 4 + q];
            o.z = w[2 * 4 + q];
            o.w = w[3 * 4 + q];
            as[q] = o;
        }
    }
}

// Fused edge pass (best configuration, R22): bin CHB edges by relation in
// LDS, then per relation MFMA-batch 16 edges/wave (native fp8 MFMA,
// stationary W, S/D register prefetch). 490 total blocks ~ 1.9/CU.
__global__ __launch_bounds__(BT, 6) void edge_kernel(
    const unsigned char* __restrict__ AS8,
    const unsigned char* __restrict__ Wp8,
    const float* __restrict__ absent_bias,
    const int* __restrict__ ei, const int* __restrict__ et,
    const int* __restrict__ nei, const int* __restrict__ net,
    float* __restrict__ out)
{
    __shared__ unsigned list[N_REL * CAP];   // 20480 B
    __shared__ unsigned cnt[N_REL];
    __shared__ float red[8];
    if (threadIdx.x < N_REL) cnt[threadIdx.x] = 0u;
    __syncthreads();

    int blk = blockIdx.x;
    bool isneg = blk >= NBLK;
    int lb = isneg ? blk - NBLK : blk;
    const int* Es = isneg ? nei : ei;
    const int* Et = isneg ? net : et;
    float sign = isneg ? 1.0f : -1.0f;
    int base = lb * CHB;
    int elim = min(base + CHB, E_EDGES);

    for (int e = base + threadIdx.x; e < elim; e += BT) {
        int s = Es[e];
        int d = Es[E_EDGES + e];
        int r = Et[e];
        unsigned rank = atomicAdd(&cnt[r], 1u);
        if (rank < CAP) list[r * CAP + rank] = (unsigned)s | ((unsigned)d << 16);
    }
    __syncthreads();

    int lane = threadIdx.x & 63;
    int wid  = threadIdx.x >> 6;    // 0..7
    int n16  = lane & 15;
    int quad = lane >> 4;
    float loss = 0.0f;

    for (int r = 0; r < N_REL; ++r) {
        int n_r = min((int)cnt[r], CAP);
        if (n_r == 0) continue;
        float bias = absent_bias[r];
        // stationary fp8 A-operand: one b128 per mt row-tile (kept in VGPRs)
        uint4 wfm[4];
        #pragma unroll
        for (int mt = 0; mt < 4; ++mt)
            wfm[mt] = *(const uint4*)(Wp8 + ((r * 64 + mt * 16 + n16) << 6) + quad * 16);

        // pipelined group loop (stride 8 waves): prefetch next group's S/D
        int g = wid;
        bool valid = false;
        uint4 S = {0, 0, 0, 0}, D = {0, 0, 0, 0};
        if (g * 16 < n_r) {
            int idx = g * 16 + n16;
            valid = idx < n_r;
            unsigned rec = list[r * CAP + (valid ? idx : 0)];
            S = *(const uint4*)(AS8 + ((size_t)(rec & 0xFFFF) << 6) + quad * 16);
            D = *(const uint4*)(AS8 + ((size_t)(rec >> 16) << 6) + quad * 16);
        }
        while (g * 16 < n_r) {
            int g2 = g + 8;
            bool valid2 = false;
            uint4 S2 = {0, 0, 0, 0}, D2 = {0, 0, 0, 0};
            if (g2 * 16 < n_r) {
                int idx2 = g2 * 16 + n16;
                valid2 = idx2 < n_r;
                unsigned rec2 = list[r * CAP + (valid2 ? idx2 : 0)];
                S2 = *(const uint4*)(AS8 + ((size_t)(rec2 & 0xFFFF) << 6) + quad * 16);
                D2 = *(const uint4*)(AS8 + ((size_t)(rec2 >> 16) << 6) + quad * 16);
            }

            long long bD0 = pack64(D.x, D.y);   // c=0 slots (first K=32)
            long long bD1 = pack64(D.z, D.w);   // c=1 slots
            floatx4 ac[4];
            #pragma unroll
            for (int mt = 0; mt < 4; ++mt) {
                floatx4 z = {0.0f, 0.0f, 0.0f, 0.0f};
                z = __builtin_amdgcn_mfma_f32_16x16x32_fp8_fp8(
                        pack64(wfm[mt].x, wfm[mt].y), bD0, z, 0, 0, 0);
                ac[mt] = __builtin_amdgcn_mfma_f32_16x16x32_fp8_fp8(
                        pack64(wfm[mt].z, wfm[mt].w), bD1, z, 0, 0, 0);
            }
            // lane holds P[m = mt*16 + quad*4 + reg][n16]; S dword mt = those m's
            unsigned sw[4] = {S.x, S.y, S.z, S.w};
            float d0 = 0.0f, d1 = 0.0f;
            #pragma unroll
            for (int mt = 0; mt < 4; mt += 2) {
                floatx2 lo0 = __builtin_amdgcn_cvt_pk_f32_fp8((int)sw[mt], false);
                floatx2 hi0 = __builtin_amdgcn_cvt_pk_f32_fp8((int)sw[mt], true);
                floatx2 lo1 = __builtin_amdgcn_cvt_pk_f32_fp8((int)sw[mt + 1], false);
                floatx2 hi1 = __builtin_amdgcn_cvt_pk_f32_fp8((int)sw[mt + 1], true);
                d0 = fmaf(lo0.x, ac[mt][0], d0);
                d1 = fmaf(lo1.x, ac[mt + 1][0], d1);
                d0 = fmaf(lo0.y, ac[mt][1], d0);
                d1 = fmaf(lo1.y, ac[mt + 1][1], d1);
                d0 = fmaf(hi0.x, ac[mt][2], d0);
                d1 = fmaf(hi1.x, ac[mt + 1][2], d1);
                d0 = fmaf(hi0.y, ac[mt][3], d0);
                d1 = fmaf(hi1.y, ac[mt + 1][3], d1);
            }
            float dot = d0 + d1;
            dot += __shfl_xor(dot, 16);
            dot += __shfl_xor(dot, 32);
            if (quad == 0 && valid) {
                float x = sign * (dot + bias);
                loss += fmaxf(x, 0.0f) + __logf(1.0f + __expf(-fabsf(x)));
            }

            g = g2; valid = valid2; S = S2; D = D2;
        }
    }

    loss += __shfl_xor(loss, 1);
    loss += __shfl_xor(loss, 2);
    loss += __shfl_xor(loss, 4);
    loss += __shfl_xor(loss, 8);
    loss += __shfl_xor(loss, 16);
    loss += __shfl_xor(loss, 32);
    if (lane == 0) red[wid] = loss;
    __syncthreads();
    if (threadIdx.x == 0) {
        float t = red[0] + red[1] + red[2] + red[3]
                + red[4] + red[5] + red[6] + red[7];
        atomicAdd(out, t * (1.0f / (float)E_EDGES));
    }
}

extern "C" void kernel_launch(void* const* d_in, const int* in_sizes, int n_in,
                              void* d_out, int out_size, void* d_ws, size_t ws_size,
                              hipStream_t stream) {
    const float* assign = (const float*)d_in[0];
    const float* icl    = (const float*)d_in[1];
    const float* la     = (const float*)d_in[2];
    const float* ab     = (const float*)d_in[3];
    const int*   ei     = (const int*)d_in[4];
    const int*   et     = (const int*)d_in[5];
    const int*   nei    = (const int*)d_in[6];
    const int*   net    = (const int*)d_in[7];
    float* out = (float*)d_out;

    // workspace: Wp8 32KB (pad 64KB) | AS8 3.2MB
    char* basep = (char*)d_ws;
    unsigned char* Wp8 = (unsigned char*)basep;
    unsigned char* AS8 = (unsigned char*)(basep + 65536);

    prep_kernel<<<256, 256, 0, stream>>>(assign, icl, la, Wp8, AS8, out);
    edge_kernel<<<2 * NBLK, BT, 0, stream>>>(AS8, Wp8, ab, ei, et, nei, net, out);
}